// Round 1
// baseline (2086.272 us; speedup 1.0000x reference)
//
#include <hip/hip_runtime.h>
#include <stdint.h>

// ---------- types ----------
typedef unsigned short u16;
typedef short short8 __attribute__((ext_vector_type(8)));
typedef __bf16 bf16x8 __attribute__((ext_vector_type(8)));
typedef float f32x4 __attribute__((ext_vector_type(4)));

__device__ __forceinline__ u16 f2bf(float f) {
  uint32_t u = __float_as_uint(f);
  u += 0x7fffu + ((u >> 16) & 1u);   // RNE
  return (u16)(u >> 16);
}
__device__ __forceinline__ float bf2f(u16 h) {
  return __uint_as_float(((uint32_t)h) << 16);
}
__device__ __forceinline__ f32x4 mfma16(short8 a, short8 b, f32x4 c) {
  return __builtin_amdgcn_mfma_f32_16x16x32_bf16(
      __builtin_bit_cast(bf16x8, a), __builtin_bit_cast(bf16x8, b), c, 0, 0, 0);
}
// async global->LDS, 16B per lane; LDS dest must be the wave-uniform base.
__device__ __forceinline__ void gld_lds16(const u16* g, u16* lds_base) {
  __builtin_amdgcn_global_load_lds(
      (__attribute__((address_space(1))) void*)g,
      (__attribute__((address_space(3))) void*)lds_base, 16, 0, 0);
}

// ---------- fp32 -> bf16 convert (8 elem/thread) ----------
__global__ __launch_bounds__(256) void cvt_bf16(const float* __restrict__ s,
                                                u16* __restrict__ d) {
  int i = blockIdx.x * 256 + threadIdx.x;
  const float4* s4 = (const float4*)s;
  float4 a = s4[2 * i], b = s4[2 * i + 1];
  uint4 o;
  o.x = (uint32_t)f2bf(a.x) | ((uint32_t)f2bf(a.y) << 16);
  o.y = (uint32_t)f2bf(a.z) | ((uint32_t)f2bf(a.w) << 16);
  o.z = (uint32_t)f2bf(b.x) | ((uint32_t)f2bf(b.y) << 16);
  o.w = (uint32_t)f2bf(b.z) | ((uint32_t)f2bf(b.w) << 16);
  ((uint4*)d)[i] = o;
}

// ---------- NT GEMM: C[4096x4096] = A[4096x4096] * W[4096x4096]^T ----------
// m97 structure: 128x128 tile, BK=64, 4 waves (2x2, 64x64 each), global_load_lds.
// MODE 0: bf16 out at [(b*16+h)][s][d]   (Q,K for attention)
// MODE 1: bf16 out transposed [(b*16+h)][d][s]  (V^T for attention PV)
// MODE 2: fp32 out row-major [m][n]      (final projection)
template <int MODE>
__global__ __launch_bounds__(256) void gemm_nt(const u16* __restrict__ A,
                                               const u16* __restrict__ W,
                                               void* __restrict__ outp) {
  constexpr int Kd = 4096;
  __shared__ u16 As[128 * 64];
  __shared__ u16 Ws[128 * 64];
  const int tid = threadIdx.x;
  const int wid = tid >> 6, l = tid & 63;
  const int lg = l >> 4, lc = l & 15;
  const int n0 = blockIdx.x * 128, m0 = blockIdx.y * 128;
  const int wm = wid >> 1, wn = wid & 1;

  f32x4 acc[4][4];
#pragma unroll
  for (int i = 0; i < 4; ++i)
#pragma unroll
    for (int j = 0; j < 4; ++j) acc[i][j] = (f32x4)0.0f;

  const int srow = l >> 3;       // row within 8-row chunk
  const int scol = (l & 7) * 8;  // k element within chunk row

  for (int k0 = 0; k0 < Kd; k0 += 64) {
#pragma unroll
    for (int i = 0; i < 4; ++i) {
      int c = wid * 4 + i;       // chunk 0..15, 1KB each
      int row = c * 8 + srow;
      gld_lds16(&A[(size_t)(m0 + row) * Kd + k0 + scol], &As[c * 512]);
      gld_lds16(&W[(size_t)(n0 + row) * Kd + k0 + scol], &Ws[c * 512]);
    }
    __syncthreads();  // drains vmcnt -> LDS tiles ready
#pragma unroll
    for (int kk = 0; kk < 2; ++kk) {
      short8 af[4], bfr[4];
      const int ko = kk * 32 + lg * 8;
#pragma unroll
      for (int mi = 0; mi < 4; ++mi)
        af[mi] = *(const short8*)&As[(wm * 64 + mi * 16 + lc) * 64 + ko];
#pragma unroll
      for (int ni = 0; ni < 4; ++ni)
        bfr[ni] = *(const short8*)&Ws[(wn * 64 + ni * 16 + lc) * 64 + ko];
#pragma unroll
      for (int mi = 0; mi < 4; ++mi)
#pragma unroll
        for (int ni = 0; ni < 4; ++ni)
          acc[mi][ni] = mfma16(af[mi], bfr[ni], acc[mi][ni]);
    }
    __syncthreads();  // WAR before next stage
  }

  const int gr0 = m0 + wm * 64, gc0 = n0 + wn * 64;
#pragma unroll
  for (int mi = 0; mi < 4; ++mi)
#pragma unroll
    for (int ni = 0; ni < 4; ++ni)
#pragma unroll
      for (int r = 0; r < 4; ++r) {
        float v = acc[mi][ni][r];
        int gr = gr0 + mi * 16 + lg * 4 + r;  // m index (C/D row)
        int gc = gc0 + ni * 16 + lc;          // n index (C/D col)
        if constexpr (MODE == 0) {
          ((u16*)outp)[((size_t)(((gr >> 11) * 16 + (gc >> 8)) * 2048 +
                                 (gr & 2047))) * 256 + (gc & 255)] = f2bf(v);
        } else if constexpr (MODE == 1) {
          ((u16*)outp)[(size_t)((gr >> 11) * 4096 + gc) * 2048 + (gr & 2047)] =
              f2bf(v);
        } else {
          ((float*)outp)[(size_t)gr * 4096 + gc] = v;
        }
      }
}

// ---------- GPT-J interleaved RoPE on Q,K (first 64 dims/head), in place ----------
__global__ __launch_bounds__(256) void rope_qk(u16* __restrict__ Qb,
                                               u16* __restrict__ Kb,
                                               const int* __restrict__ pos) {
  int idx = blockIdx.x * 256 + threadIdx.x;  // [2][32 bh][2048 s][32 pairs]
  int pair = idx & 31;
  int s = (idx >> 5) & 2047;
  int bh = (idx >> 16) & 31;
  u16* T = (idx >> 21) ? Kb : Qb;
  float p = (float)pos[s];
  float inv = powf(10000.0f, -(float)pair * (1.0f / 32.0f));
  float ang = p * inv, sn, cs;
  sincosf(ang, &sn, &cs);
  u16* base = T + ((size_t)bh * 2048 + s) * 256 + pair * 2;
  float x1 = bf2f(base[0]), x2 = bf2f(base[1]);
  base[0] = f2bf(x1 * cs - x2 * sn);
  base[1] = f2bf(x2 * cs + x1 * sn);
}

// ---------- causal flash attention ----------
// grid (S/64, B*H); 4 waves/block, 16 q-rows/wave; KV tiles of 32.
// Q,K: [bh][s][256] bf16; Vt: [bh][256 d][2048 s] bf16; ctx out: [b*2048+s][4096] bf16.
__global__ __launch_bounds__(256) void flash_attn(const u16* __restrict__ Q,
                                                  const u16* __restrict__ K,
                                                  const u16* __restrict__ Vt,
                                                  u16* __restrict__ ctx) {
  const int bh = blockIdx.y;
  const int q0 = blockIdx.x * 64;
  const int tid = threadIdx.x, wid = tid >> 6, l = tid & 63;
  const int lg = l >> 4, lc = l & 15;
  const u16* Qh = Q + (size_t)bh * 2048 * 256;
  const u16* Kh = K + (size_t)bh * 2048 * 256;
  const u16* Vh = Vt + (size_t)bh * 256 * 2048;
  const int qr = q0 + wid * 16;

  short8 qf[8];
#pragma unroll
  for (int kk = 0; kk < 8; ++kk)
    qf[kk] = *(const short8*)&Qh[(size_t)(qr + lc) * 256 + kk * 32 + lg * 8];

  f32x4 o[16];
#pragma unroll
  for (int nf = 0; nf < 16; ++nf) o[nf] = (f32x4)0.0f;
  float mrow[4] = {-1e30f, -1e30f, -1e30f, -1e30f};
  float lrow[4] = {0.f, 0.f, 0.f, 0.f};

  __shared__ u16 P[4][16 * 40];  // per-wave P^T staging, stride 40 kills bank conflicts
  u16* myP = P[wid];

  const int ntiles = (q0 >> 5) + 2;
  for (int t = 0; t < ntiles; ++t) {
    const int kv0 = t * 32;
    f32x4 s2[2];
    s2[0] = (f32x4)0.0f;
    s2[1] = (f32x4)0.0f;
#pragma unroll
    for (int kk = 0; kk < 8; ++kk) {
      short8 k0f = *(const short8*)&Kh[(size_t)(kv0 + lc) * 256 + kk * 32 + lg * 8];
      short8 k1f = *(const short8*)&Kh[(size_t)(kv0 + 16 + lc) * 256 + kk * 32 + lg * 8];
      s2[0] = mfma16(qf[kk], k0f, s2[0]);
      s2[1] = mfma16(qf[kk], k1f, s2[1]);
    }
    float alpha[4];
#pragma unroll
    for (int r = 0; r < 4; ++r) {
      const int qrow = qr + lg * 4 + r;
      float v0 = (kv0 + lc <= qrow) ? s2[0][r] * 0.0625f : -1e30f;
      float v1 = (kv0 + 16 + lc <= qrow) ? s2[1][r] * 0.0625f : -1e30f;
      float pmr = fmaxf(v0, v1);
      pmr = fmaxf(pmr, __shfl_xor(pmr, 1));
      pmr = fmaxf(pmr, __shfl_xor(pmr, 2));
      pmr = fmaxf(pmr, __shfl_xor(pmr, 4));
      pmr = fmaxf(pmr, __shfl_xor(pmr, 8));
      float mn = fmaxf(mrow[r], pmr);
      alpha[r] = __expf(mrow[r] - mn);
      mrow[r] = mn;
      float p0 = __expf(v0 - mn), p1 = __expf(v1 - mn);
      myP[(lg * 4 + r) * 40 + lc] = f2bf(p0);
      myP[(lg * 4 + r) * 40 + 16 + lc] = f2bf(p1);
      float ps = p0 + p1;
      ps += __shfl_xor(ps, 1);
      ps += __shfl_xor(ps, 2);
      ps += __shfl_xor(ps, 4);
      ps += __shfl_xor(ps, 8);
      lrow[r] = lrow[r] * alpha[r] + ps;
    }
#pragma unroll
    for (int nf = 0; nf < 16; ++nf) {
      f32x4 t4 = o[nf];
      t4[0] *= alpha[0]; t4[1] *= alpha[1];
      t4[2] *= alpha[2]; t4[3] *= alpha[3];
      o[nf] = t4;
    }
    __syncthreads();  // cross-lane P visibility (uniform trip count per block)
    short8 pf = *(const short8*)&myP[lc * 40 + lg * 8];
#pragma unroll
    for (int nf = 0; nf < 16; ++nf) {
      short8 vf = *(const short8*)&Vh[(size_t)(nf * 16 + lc) * 2048 + kv0 + lg * 8];
      o[nf] = mfma16(pf, vf, o[nf]);
    }
    __syncthreads();  // WAR on P before next tile
  }

  float inv[4];
#pragma unroll
  for (int r = 0; r < 4; ++r) inv[r] = 1.0f / lrow[r];
  const int crow0 = (bh >> 4) * 2048 + qr;
  const int ccol0 = (bh & 15) * 256;
#pragma unroll
  for (int nf = 0; nf < 16; ++nf)
#pragma unroll
    for (int r = 0; r < 4; ++r)
      ctx[(size_t)(crow0 + lg * 4 + r) * 4096 + ccol0 + nf * 16 + lc] =
          f2bf(o[nf][r] * inv[r]);
}

// ---------- launcher ----------
extern "C" void kernel_launch(void* const* d_in, const int* in_sizes, int n_in,
                              void* d_out, int out_size, void* d_ws, size_t ws_size,
                              hipStream_t stream) {
  const float* hidden = (const float*)d_in[0];
  const float* Wq = (const float*)d_in[1];
  const float* Wk = (const float*)d_in[2];
  const float* Wv = (const float*)d_in[3];
  const float* Wo = (const float*)d_in[4];
  const int* pos = (const int*)d_in[5];

  const size_t NEL = 16777216;  // 4096*4096
  if (ws_size < 6 * NEL * sizeof(u16)) return;  // need 192 MB scratch

  u16* hb = (u16*)d_ws;      // hidden bf16; reused as ctx after QKV GEMMs
  u16* wq = hb + NEL;
  u16* wk = wq + NEL;
  u16* wv = wk + NEL;
  u16* wo = wv + NEL;
  u16* vt = wo + NEL;        // V^T [bh][d][s]
  u16* ctx = hb;
  u16* qb = (u16*)d_out;     // Q,K live in d_out (exactly 64MB); overwritten by final GEMM
  u16* kb = qb + NEL;

  cvt_bf16<<<8192, 256, 0, stream>>>(hidden, hb);
  cvt_bf16<<<8192, 256, 0, stream>>>(Wq, wq);
  cvt_bf16<<<8192, 256, 0, stream>>>(Wk, wk);
  cvt_bf16<<<8192, 256, 0, stream>>>(Wv, wv);
  cvt_bf16<<<8192, 256, 0, stream>>>(Wo, wo);

  dim3 gg(32, 32);
  gemm_nt<0><<<gg, 256, 0, stream>>>(hb, wq, qb);
  gemm_nt<0><<<gg, 256, 0, stream>>>(hb, wk, kb);
  gemm_nt<1><<<gg, 256, 0, stream>>>(hb, wv, vt);

  rope_qk<<<16384, 256, 0, stream>>>(qb, kb, pos);

  flash_attn<<<dim3(32, 32), 256, 0, stream>>>(qb, kb, vt, ctx);

  gemm_nt<2><<<gg, 256, 0, stream>>>(ctx, wo, d_out);
}

// Round 2
// 1423.556 us; speedup vs baseline: 1.4655x; 1.4655x over previous
//
#include <hip/hip_runtime.h>
#include <stdint.h>

// ---------- types ----------
typedef unsigned short u16;
typedef short short8 __attribute__((ext_vector_type(8)));
typedef __bf16 bf16x8 __attribute__((ext_vector_type(8)));
typedef float f32x4 __attribute__((ext_vector_type(4)));

__device__ __forceinline__ u16 f2bf(float f) {
  uint32_t u = __float_as_uint(f);
  u += 0x7fffu + ((u >> 16) & 1u);   // RNE
  return (u16)(u >> 16);
}
__device__ __forceinline__ float bf2f(u16 h) {
  return __uint_as_float(((uint32_t)h) << 16);
}
__device__ __forceinline__ f32x4 mfma16(short8 a, short8 b, f32x4 c) {
  return __builtin_amdgcn_mfma_f32_16x16x32_bf16(
      __builtin_bit_cast(bf16x8, a), __builtin_bit_cast(bf16x8, b), c, 0, 0, 0);
}
__device__ __forceinline__ uint32_t cvtpk_bf16(float lo, float hi) {
  uint32_t r;
  asm("v_cvt_pk_bf16_f32 %0, %1, %2" : "=v"(r) : "v"(lo), "v"(hi));
  return r;
}
// async global->LDS, 16B per lane; LDS dest must be the wave-uniform base.
__device__ __forceinline__ void gld_lds16(const u16* g, u16* lds_base) {
  __builtin_amdgcn_global_load_lds(
      (__attribute__((address_space(1))) void*)g,
      (__attribute__((address_space(3))) void*)lds_base, 16, 0, 0);
}

// ---------- fp32 -> bf16 convert (8 elem/thread) ----------
__global__ __launch_bounds__(256) void cvt_bf16(const float* __restrict__ s,
                                                u16* __restrict__ d) {
  int i = blockIdx.x * 256 + threadIdx.x;
  const float4* s4 = (const float4*)s;
  float4 a = s4[2 * i], b = s4[2 * i + 1];
  uint4 o;
  o.x = (uint32_t)f2bf(a.x) | ((uint32_t)f2bf(a.y) << 16);
  o.y = (uint32_t)f2bf(a.z) | ((uint32_t)f2bf(a.w) << 16);
  o.z = (uint32_t)f2bf(b.x) | ((uint32_t)f2bf(b.y) << 16);
  o.w = (uint32_t)f2bf(b.z) | ((uint32_t)f2bf(b.w) << 16);
  ((uint4*)d)[i] = o;
}

// ---------- NT GEMM: C[4096x4096] = A[4096x4096] * W[4096x4096]^T ----------
// m97 structure: 128x128 tile, BK=64, 4 waves (2x2, 64x64 each), global_load_lds.
// MODE 0: bf16 out at [(b*16+h)][s][d]   (Q,K for attention)
// MODE 1: bf16 out transposed [(b*16+h)][d][s]  (V^T for attention PV)
// MODE 2: fp32 out row-major [m][n]      (final projection)
// oscale: multiplied into every output (Q gets log2(e)/16 so flash runs in exp2 domain)
template <int MODE>
__global__ __launch_bounds__(256) void gemm_nt(const u16* __restrict__ A,
                                               const u16* __restrict__ W,
                                               void* __restrict__ outp,
                                               float oscale) {
  constexpr int Kd = 4096;
  __shared__ u16 As[128 * 64];
  __shared__ u16 Ws[128 * 64];
  const int tid = threadIdx.x;
  const int wid = tid >> 6, l = tid & 63;
  const int lg = l >> 4, lc = l & 15;
  const int n0 = blockIdx.x * 128, m0 = blockIdx.y * 128;
  const int wm = wid >> 1, wn = wid & 1;

  f32x4 acc[4][4];
#pragma unroll
  for (int i = 0; i < 4; ++i)
#pragma unroll
    for (int j = 0; j < 4; ++j) acc[i][j] = (f32x4)0.0f;

  const int srow = l >> 3;       // row within 8-row chunk
  const int scol = (l & 7) * 8;  // k element within chunk row

  for (int k0 = 0; k0 < Kd; k0 += 64) {
#pragma unroll
    for (int i = 0; i < 4; ++i) {
      int c = wid * 4 + i;       // chunk 0..15, 1KB each
      int row = c * 8 + srow;
      gld_lds16(&A[(size_t)(m0 + row) * Kd + k0 + scol], &As[c * 512]);
      gld_lds16(&W[(size_t)(n0 + row) * Kd + k0 + scol], &Ws[c * 512]);
    }
    __syncthreads();  // drains vmcnt -> LDS tiles ready
#pragma unroll
    for (int kk = 0; kk < 2; ++kk) {
      short8 af[4], bfr[4];
      const int ko = kk * 32 + lg * 8;
#pragma unroll
      for (int mi = 0; mi < 4; ++mi)
        af[mi] = *(const short8*)&As[(wm * 64 + mi * 16 + lc) * 64 + ko];
#pragma unroll
      for (int ni = 0; ni < 4; ++ni)
        bfr[ni] = *(const short8*)&Ws[(wn * 64 + ni * 16 + lc) * 64 + ko];
#pragma unroll
      for (int mi = 0; mi < 4; ++mi)
#pragma unroll
        for (int ni = 0; ni < 4; ++ni)
          acc[mi][ni] = mfma16(af[mi], bfr[ni], acc[mi][ni]);
    }
    __syncthreads();  // WAR before next stage
  }

  const int gr0 = m0 + wm * 64, gc0 = n0 + wn * 64;
#pragma unroll
  for (int mi = 0; mi < 4; ++mi)
#pragma unroll
    for (int ni = 0; ni < 4; ++ni)
#pragma unroll
      for (int r = 0; r < 4; ++r) {
        float v = acc[mi][ni][r] * oscale;
        int gr = gr0 + mi * 16 + lg * 4 + r;  // m index (C/D row)
        int gc = gc0 + ni * 16 + lc;          // n index (C/D col)
        if constexpr (MODE == 0) {
          ((u16*)outp)[((size_t)(((gr >> 11) * 16 + (gc >> 8)) * 2048 +
                                 (gr & 2047))) * 256 + (gc & 255)] = f2bf(v);
        } else if constexpr (MODE == 1) {
          ((u16*)outp)[(size_t)((gr >> 11) * 4096 + gc) * 2048 + (gr & 2047)] =
              f2bf(v);
        } else {
          ((float*)outp)[(size_t)gr * 4096 + gc] = v;
        }
      }
}

// ---------- GPT-J interleaved RoPE on Q,K (first 64 dims/head), in place ----------
// Linear rotation commutes with the Q pre-scale, so running it after the scaled
// Q-GEMM is exact.
__global__ __launch_bounds__(256) void rope_qk(u16* __restrict__ Qb,
                                               u16* __restrict__ Kb,
                                               const int* __restrict__ pos) {
  int idx = blockIdx.x * 256 + threadIdx.x;  // [2][32 bh][2048 s][32 pairs]
  int pair = idx & 31;
  int s = (idx >> 5) & 2047;
  int bh = (idx >> 16) & 31;
  u16* T = (idx >> 21) ? Kb : Qb;
  float p = (float)pos[s];
  float inv = powf(10000.0f, -(float)pair * (1.0f / 32.0f));
  float ang = p * inv, sn, cs;
  sincosf(ang, &sn, &cs);
  u16* base = T + ((size_t)bh * 2048 + s) * 256 + pair * 2;
  float x1 = bf2f(base[0]), x2 = bf2f(base[1]);
  base[0] = f2bf(x1 * cs - x2 * sn);
  base[1] = f2bf(x2 * cs + x1 * sn);
}

// ---------- causal flash attention, swapped-operand, 1 wave / block ----------
// Flat grid of 4096 single-wave blocks; 16 q-rows per wave; KV tiles of 32.
// Q pre-scaled by log2(e)/16 -> softmax in exp2 domain.
// Swapped QK^T: mfma(A=K, B=Q) => D[kv][q], lane: q = lane&15 (one q-row per
// lane group-column), kv = (lane>>4)*4 + reg. Row-softmax = 7 in-lane ops +
// 2 shfl_xor for ALL 16 q rows at once (vs 32 shfls before).
// Q,K: [bh][s][256] bf16; Vt: [bh][256 d][2048 s] bf16; ctx: [b*2048+s][4096] bf16.
__global__ __launch_bounds__(64) void flash_attn(const u16* __restrict__ Q,
                                                 const u16* __restrict__ K,
                                                 const u16* __restrict__ Vt,
                                                 u16* __restrict__ ctx) {
  // XCD swizzle: consecutive hardware dispatch (round-robin over 8 XCDs) gets
  // bid' contiguous per XCD => each XCD owns 4 heads => K/V L2-local.
  const int bid = blockIdx.x;
  const int bidp = (bid & 7) * 512 + (bid >> 3);
  const int bh = bidp >> 7;          // 0..31
  const int qi = bidp & 127;         // 0..127
  const int qr = 2032 - qi * 16;     // longest-first within each XCD
  const int l = threadIdx.x;
  const int lg = l >> 4, lc = l & 15;

  const u16* Qh = Q + (size_t)bh * 2048 * 256;
  const u16* Kh = K + (size_t)bh * 2048 * 256;
  const u16* Vh = Vt + (size_t)bh * 256 * 2048;

  short8 qf[8];
#pragma unroll
  for (int kk = 0; kk < 8; ++kk)
    qf[kk] = *(const short8*)&Qh[(size_t)(qr + lc) * 256 + kk * 32 + lg * 8];

  f32x4 o[16];
#pragma unroll
  for (int nf = 0; nf < 16; ++nf) o[nf] = (f32x4)0.0f;
  float mrow = -1e30f;  // per-lane: running max for q = qr+lc (replicated over lg)
  float lrow = 0.0f;

  __shared__ u16 P[16 * 40];  // [q][kv] bf16, stride 40 u16 (80B) kills bank conflicts
  uint32_t* Pw = (uint32_t*)P;

  const int ntiles = qr / 32 + 1;  // exact causal trip count for this wave
  for (int t = 0; t < ntiles; ++t) {
    const int kv0 = t * 32;
    f32x4 s0 = (f32x4)0.0f, s1 = (f32x4)0.0f;
#pragma unroll
    for (int kk = 0; kk < 8; ++kk) {
      short8 k0 = *(const short8*)&Kh[(size_t)(kv0 + lc) * 256 + kk * 32 + lg * 8];
      short8 k1 = *(const short8*)&Kh[(size_t)(kv0 + 16 + lc) * 256 + kk * 32 + lg * 8];
      s0 = mfma16(k0, qf[kk], s0);  // D[kv][q]
      s1 = mfma16(k1, qf[kk], s1);
    }
    float sv[8];
#pragma unroll
    for (int r = 0; r < 4; ++r) { sv[r] = s0[r]; sv[4 + r] = s1[r]; }
    if (kv0 + 31 > qr) {  // wave-uniform: only diagonal tiles need the mask
#pragma unroll
      for (int f = 0; f < 2; ++f)
#pragma unroll
        for (int r = 0; r < 4; ++r) {
          int kvg = kv0 + f * 16 + lg * 4 + r;
          if (kvg > qr + lc) sv[f * 4 + r] = -1e30f;
        }
    }
    // row max for q = qr+lc: 7 in-lane + 2 shfl (covers all 16 rows at once)
    float m8 = fmaxf(fmaxf(fmaxf(sv[0], sv[1]), fmaxf(sv[2], sv[3])),
                     fmaxf(fmaxf(sv[4], sv[5]), fmaxf(sv[6], sv[7])));
    float pm = fmaxf(m8, __shfl_xor(m8, 16));
    pm = fmaxf(pm, __shfl_xor(pm, 32));
    // exact defer-max: rescale only if some row's max actually grew
    if (__ballot(pm > mrow)) {
      float mn = fmaxf(mrow, pm);
      float alpha = __builtin_amdgcn_exp2f(mrow - mn);
      lrow *= alpha;
      float aa[4];
#pragma unroll
      for (int r = 0; r < 4; ++r) aa[r] = __shfl(alpha, lg * 4 + r);
#pragma unroll
      for (int nf = 0; nf < 16; ++nf) {
        f32x4 t4 = o[nf];
#pragma unroll
        for (int r = 0; r < 4; ++r) t4[r] *= aa[r];
        o[nf] = t4;
      }
      mrow = mn;
    }
    float p[8];
#pragma unroll
    for (int j = 0; j < 8; ++j) p[j] = __builtin_amdgcn_exp2f(sv[j] - mrow);
    float ps = ((p[0] + p[1]) + (p[2] + p[3])) + ((p[4] + p[5]) + (p[6] + p[7]));
    ps += __shfl_xor(ps, 16);
    ps += __shfl_xor(ps, 32);
    lrow += ps;
    // P[q=lc][kv] -> LDS (same-wave DS ops are in-order; compiler fence only)
    asm volatile("" ::: "memory");
    Pw[lc * 20 + lg * 2 + 0] = cvtpk_bf16(p[0], p[1]);
    Pw[lc * 20 + lg * 2 + 1] = cvtpk_bf16(p[2], p[3]);
    Pw[lc * 20 + 8 + lg * 2 + 0] = cvtpk_bf16(p[4], p[5]);
    Pw[lc * 20 + 8 + lg * 2 + 1] = cvtpk_bf16(p[6], p[7]);
    asm volatile("" ::: "memory");
    short8 pf = *(const short8*)&P[lc * 40 + lg * 8];  // A-frag: row q=lc, kv=lg*8..+7
#pragma unroll
    for (int nf = 0; nf < 16; ++nf) {
      short8 vf = *(const short8*)&Vh[(size_t)(nf * 16 + lc) * 2048 + kv0 + lg * 8];
      o[nf] = mfma16(pf, vf, o[nf]);  // D[q][d]: q = lg*4+r, d = nf*16+lc
    }
    asm volatile("" ::: "memory");  // WAR: keep next tile's P writes after this read
  }

  float il = 1.0f / lrow;
  float ia[4];
#pragma unroll
  for (int r = 0; r < 4; ++r) ia[r] = __shfl(il, lg * 4 + r);
  const int crow0 = (bh >> 4) * 2048 + qr;
  const int ccol0 = (bh & 15) * 256;
#pragma unroll
  for (int nf = 0; nf < 16; ++nf)
#pragma unroll
    for (int r = 0; r < 4; ++r)
      ctx[(size_t)(crow0 + lg * 4 + r) * 4096 + ccol0 + nf * 16 + lc] =
          f2bf(o[nf][r] * ia[r]);
}

// ---------- launcher ----------
extern "C" void kernel_launch(void* const* d_in, const int* in_sizes, int n_in,
                              void* d_out, int out_size, void* d_ws, size_t ws_size,
                              hipStream_t stream) {
  const float* hidden = (const float*)d_in[0];
  const float* Wq = (const float*)d_in[1];
  const float* Wk = (const float*)d_in[2];
  const float* Wv = (const float*)d_in[3];
  const float* Wo = (const float*)d_in[4];
  const int* pos = (const int*)d_in[5];

  const size_t NEL = 16777216;  // 4096*4096
  if (ws_size < 6 * NEL * sizeof(u16)) return;  // need 192 MB scratch

  u16* hb = (u16*)d_ws;      // hidden bf16; reused as ctx after QKV GEMMs
  u16* wq = hb + NEL;
  u16* wk = wq + NEL;
  u16* wv = wk + NEL;
  u16* wo = wv + NEL;
  u16* vt = wo + NEL;        // V^T [bh][d][s]
  u16* ctx = hb;
  u16* qb = (u16*)d_out;     // Q,K live in d_out (exactly 64MB); overwritten by final GEMM
  u16* kb = qb + NEL;

  cvt_bf16<<<8192, 256, 0, stream>>>(hidden, hb);
  cvt_bf16<<<8192, 256, 0, stream>>>(Wq, wq);
  cvt_bf16<<<8192, 256, 0, stream>>>(Wk, wk);
  cvt_bf16<<<8192, 256, 0, stream>>>(Wv, wv);
  cvt_bf16<<<8192, 256, 0, stream>>>(Wo, wo);

  dim3 gg(32, 32);
  // Q pre-scaled by log2(e)/16 so flash softmax runs in exp2 domain.
  gemm_nt<0><<<gg, 256, 0, stream>>>(hb, wq, qb, 0.09016844f);
  gemm_nt<0><<<gg, 256, 0, stream>>>(hb, wk, kb, 1.0f);
  gemm_nt<1><<<gg, 256, 0, stream>>>(hb, wv, vt, 1.0f);

  rope_qk<<<16384, 256, 0, stream>>>(qb, kb, pos);

  flash_attn<<<4096, 64, 0, stream>>>(qb, kb, vt, ctx);

  gemm_nt<2><<<gg, 256, 0, stream>>>(ctx, wo, d_out, 1.0f);
}

// Round 3
// 1136.809 us; speedup vs baseline: 1.8352x; 1.2522x over previous
//
#include <hip/hip_runtime.h>
#include <stdint.h>

// ---------- types ----------
typedef unsigned short u16;
typedef short short8 __attribute__((ext_vector_type(8)));
typedef __bf16 bf16x8 __attribute__((ext_vector_type(8)));
typedef float f32x4 __attribute__((ext_vector_type(4)));

__device__ __forceinline__ u16 f2bf(float f) {
  uint32_t u = __float_as_uint(f);
  u += 0x7fffu + ((u >> 16) & 1u);   // RNE
  return (u16)(u >> 16);
}
__device__ __forceinline__ float bf2f(u16 h) {
  return __uint_as_float(((uint32_t)h) << 16);
}
__device__ __forceinline__ f32x4 mfma16(short8 a, short8 b, f32x4 c) {
  return __builtin_amdgcn_mfma_f32_16x16x32_bf16(
      __builtin_bit_cast(bf16x8, a), __builtin_bit_cast(bf16x8, b), c, 0, 0, 0);
}
__device__ __forceinline__ uint32_t cvtpk_bf16(float lo, float hi) {
  uint32_t r;
  asm("v_cvt_pk_bf16_f32 %0, %1, %2" : "=v"(r) : "v"(lo), "v"(hi));
  return r;
}
// async global->LDS, 16B per lane; LDS dest must be the wave-uniform base.
__device__ __forceinline__ void gld_lds16(const u16* g, u16* lds_base) {
  __builtin_amdgcn_global_load_lds(
      (__attribute__((address_space(1))) void*)g,
      (__attribute__((address_space(3))) void*)lds_base, 16, 0, 0);
}

// ---------- fp32 -> bf16 convert (8 elem/thread) ----------
__global__ __launch_bounds__(256) void cvt_bf16(const float* __restrict__ s,
                                                u16* __restrict__ d) {
  int i = blockIdx.x * 256 + threadIdx.x;
  const float4* s4 = (const float4*)s;
  float4 a = s4[2 * i], b = s4[2 * i + 1];
  uint4 o;
  o.x = (uint32_t)f2bf(a.x) | ((uint32_t)f2bf(a.y) << 16);
  o.y = (uint32_t)f2bf(a.z) | ((uint32_t)f2bf(a.w) << 16);
  o.z = (uint32_t)f2bf(b.x) | ((uint32_t)f2bf(b.y) << 16);
  o.w = (uint32_t)f2bf(b.z) | ((uint32_t)f2bf(b.w) << 16);
  ((uint4*)d)[i] = o;
}

// ---------- NT GEMM: C[4096x4096] = A[4096x4096] * W[4096x4096]^T ----------
// m97 structure: 128x128 tile, BK=64, 4 waves (2x2, 64x64 each), global_load_lds.
// MODE 0: bf16 out at [(b*16+h)][s][d]   (Q,K for attention)
// MODE 1: bf16 out transposed [(b*16+h)][d][s]  (V^T for attention PV)
// MODE 2: fp32 out row-major [m][n]      (final projection)
// oscale: multiplied into every output (Q gets log2(e)/16 so flash runs in exp2 domain)
template <int MODE>
__global__ __launch_bounds__(256) void gemm_nt(const u16* __restrict__ A,
                                               const u16* __restrict__ W,
                                               void* __restrict__ outp,
                                               float oscale) {
  constexpr int Kd = 4096;
  __shared__ u16 As[128 * 64];
  __shared__ u16 Ws[128 * 64];
  const int tid = threadIdx.x;
  const int wid = tid >> 6, l = tid & 63;
  const int lg = l >> 4, lc = l & 15;
  const int n0 = blockIdx.x * 128, m0 = blockIdx.y * 128;
  const int wm = wid >> 1, wn = wid & 1;

  f32x4 acc[4][4];
#pragma unroll
  for (int i = 0; i < 4; ++i)
#pragma unroll
    for (int j = 0; j < 4; ++j) acc[i][j] = (f32x4)0.0f;

  const int srow = l >> 3;       // row within 8-row chunk
  const int scol = (l & 7) * 8;  // k element within chunk row

  for (int k0 = 0; k0 < Kd; k0 += 64) {
#pragma unroll
    for (int i = 0; i < 4; ++i) {
      int c = wid * 4 + i;       // chunk 0..15, 1KB each
      int row = c * 8 + srow;
      gld_lds16(&A[(size_t)(m0 + row) * Kd + k0 + scol], &As[c * 512]);
      gld_lds16(&W[(size_t)(n0 + row) * Kd + k0 + scol], &Ws[c * 512]);
    }
    __syncthreads();  // drains vmcnt -> LDS tiles ready
#pragma unroll
    for (int kk = 0; kk < 2; ++kk) {
      short8 af[4], bfr[4];
      const int ko = kk * 32 + lg * 8;
#pragma unroll
      for (int mi = 0; mi < 4; ++mi)
        af[mi] = *(const short8*)&As[(wm * 64 + mi * 16 + lc) * 64 + ko];
#pragma unroll
      for (int ni = 0; ni < 4; ++ni)
        bfr[ni] = *(const short8*)&Ws[(wn * 64 + ni * 16 + lc) * 64 + ko];
#pragma unroll
      for (int mi = 0; mi < 4; ++mi)
#pragma unroll
        for (int ni = 0; ni < 4; ++ni)
          acc[mi][ni] = mfma16(af[mi], bfr[ni], acc[mi][ni]);
    }
    __syncthreads();  // WAR before next stage
  }

  const int gr0 = m0 + wm * 64, gc0 = n0 + wn * 64;
#pragma unroll
  for (int mi = 0; mi < 4; ++mi)
#pragma unroll
    for (int ni = 0; ni < 4; ++ni)
#pragma unroll
      for (int r = 0; r < 4; ++r) {
        float v = acc[mi][ni][r] * oscale;
        int gr = gr0 + mi * 16 + lg * 4 + r;  // m index (C/D row)
        int gc = gc0 + ni * 16 + lc;          // n index (C/D col)
        if constexpr (MODE == 0) {
          ((u16*)outp)[((size_t)(((gr >> 11) * 16 + (gc >> 8)) * 2048 +
                                 (gr & 2047))) * 256 + (gc & 255)] = f2bf(v);
        } else if constexpr (MODE == 1) {
          ((u16*)outp)[(size_t)((gr >> 11) * 4096 + gc) * 2048 + (gr & 2047)] =
              f2bf(v);
        } else {
          ((float*)outp)[(size_t)gr * 4096 + gc] = v;
        }
      }
}

// ---------- GPT-J interleaved RoPE on Q,K (first 64 dims/head), in place ----------
__global__ __launch_bounds__(256) void rope_qk(u16* __restrict__ Qb,
                                               u16* __restrict__ Kb,
                                               const int* __restrict__ pos) {
  int idx = blockIdx.x * 256 + threadIdx.x;  // [2][32 bh][2048 s][32 pairs]
  int pair = idx & 31;
  int s = (idx >> 5) & 2047;
  int bh = (idx >> 16) & 31;
  u16* T = (idx >> 21) ? Kb : Qb;
  float p = (float)pos[s];
  float inv = powf(10000.0f, -(float)pair * (1.0f / 32.0f));
  float ang = p * inv, sn, cs;
  sincosf(ang, &sn, &cs);
  u16* base = T + ((size_t)bh * 2048 + s) * 256 + pair * 2;
  float x1 = bf2f(base[0]), x2 = bf2f(base[1]);
  base[0] = f2bf(x1 * cs - x2 * sn);
  base[1] = f2bf(x2 * cs + x1 * sn);
}

// ---------- causal flash attention v3 ----------
// 1024 blocks = 32 bh x 32 q-blocks of 64 rows; 4 waves/block, 16 q-rows/wave.
// KV tiles of 32, K+V staged to LDS via global_load_lds, DOUBLE-BUFFERED:
// stage(t+1) issued before compute(t) -> global latency hides under compute.
// LDS dest linear (gld_lds requirement); global SOURCE pre-swizzled with the
// same XOR applied on ds_read (rule: both-sides-or-neither).
//   K tile [32 kv][256 d] u16 (512B rows): byte ^= (row&7)<<4  -> conflict-free b128
//   V tile [256 d][32 kv] u16 (64B rows):  byte ^= ((d>>1)&3)<<4
// Swapped QK^T softmax identical to verified R2 kernel.
// Q,K: [bh][s][256] bf16; Vt: [bh][256 d][2048 s] bf16; ctx: [b*2048+s][4096] bf16.
__global__ __launch_bounds__(256) void flash_attn(const u16* __restrict__ Q,
                                                  const u16* __restrict__ K,
                                                  const u16* __restrict__ Vt,
                                                  u16* __restrict__ ctx) {
  __shared__ u16 Ks[2][32 * 256];   // 16KB per buffer
  __shared__ u16 Vs[2][256 * 32];   // 16KB per buffer
  __shared__ u16 P[4][16 * 40];     // per-wave P, stride 40 u16

  // XCD swizzle (1024 % 8 == 0 -> bijective): each XCD owns 4 heads;
  // within an XCD, blocks arrive longest-first.
  const int bid = blockIdx.x;
  const int bidp = (bid & 7) * 128 + (bid >> 3);
  const int bh = bidp >> 5;           // 0..31
  const int qi = bidp & 31;           // 0..31
  const int q0 = 1984 - qi * 64;      // 64-row q block, longest first
  const int tid = threadIdx.x;
  const int wid = tid >> 6, l = tid & 63;
  const int lg = l >> 4, lc = l & 15;
  const int qr = q0 + wid * 16;       // this wave's 16 q rows

  const u16* Qh = Q + (size_t)bh * 2048 * 256;
  const u16* Kh = K + (size_t)bh * 2048 * 256;
  const u16* Vh = Vt + (size_t)bh * 256 * 2048;

  // --- staging address precompute (u16 units) ---
  // K chunk j = wid*4+jj stages LDS bytes [j*1024, j*1024+1024): lane l ->
  // row = 2j+(l>>5), colB = (l&31)*16; source col pre-XORed with (row&7)<<4.
  // V chunk j: d = j*16+(l>>2), colB = (l&3)*16; source XOR ((d>>1)&3)<<4.
  int krow[4], kcol[4], vrow[4], vcol[4];
#pragma unroll
  for (int jj = 0; jj < 4; ++jj) {
    int j = wid * 4 + jj;
    krow[jj] = 2 * j + (l >> 5);
    kcol[jj] = ((((l & 31) << 4) ^ ((krow[jj] & 7) << 4)) >> 1);
    vrow[jj] = j * 16 + (l >> 2);
    vcol[jj] = ((((l & 3) << 4) ^ (((vrow[jj] >> 1) & 3) << 4)) >> 1);
  }

  short8 qf[8];
#pragma unroll
  for (int kk = 0; kk < 8; ++kk)
    qf[kk] = *(const short8*)&Qh[(size_t)(qr + lc) * 256 + kk * 32 + lg * 8];

  f32x4 o[16];
#pragma unroll
  for (int nf = 0; nf < 16; ++nf) o[nf] = (f32x4)0.0f;
  float mrow = -1e30f;  // running max for q = qr+lc (replicated over lg)
  float lrow = 0.0f;

  uint32_t* Pw = (uint32_t*)P[wid];
  const u16* Pm = P[wid];

  // block-uniform trip count (covers wave 3's rows; earlier waves mask)
  const int ntiles = q0 / 32 + 2;

  // prologue: stage tile 0 into buffer 0
#pragma unroll
  for (int jj = 0; jj < 4; ++jj) {
    gld_lds16(Kh + (size_t)krow[jj] * 256 + kcol[jj], &Ks[0][(wid * 4 + jj) * 512]);
    gld_lds16(Vh + (size_t)vrow[jj] * 2048 + vcol[jj], &Vs[0][(wid * 4 + jj) * 512]);
  }
  __syncthreads();  // vmcnt(0) drain -> buffer 0 ready

  for (int t = 0; t < ntiles; ++t) {
    const int buf = t & 1;
    // issue next tile's stage first: flies during this tile's compute
    if (t + 1 < ntiles) {
      const int kv1 = (t + 1) << 5;
#pragma unroll
      for (int jj = 0; jj < 4; ++jj) {
        gld_lds16(Kh + (size_t)(kv1 + krow[jj]) * 256 + kcol[jj],
                  &Ks[buf ^ 1][(wid * 4 + jj) * 512]);
        gld_lds16(Vh + (size_t)vrow[jj] * 2048 + kv1 + vcol[jj],
                  &Vs[buf ^ 1][(wid * 4 + jj) * 512]);
      }
    }
    const int kv0 = t << 5;
    const char* KsB = (const char*)Ks[buf];
    const char* VsB = (const char*)Vs[buf];

    // QK^T (swapped): D[kv][q]
    f32x4 s0 = (f32x4)0.0f, s1 = (f32x4)0.0f;
#pragma unroll
    for (int kk = 0; kk < 8; ++kk) {
      const int cb = kk * 64 + lg * 16;
      short8 k0 = *(const short8*)(KsB + lc * 512 + (cb ^ ((lc & 7) << 4)));
      short8 k1 = *(const short8*)(KsB + (16 + lc) * 512 + (cb ^ ((lc & 7) << 4)));
      s0 = mfma16(k0, qf[kk], s0);
      s1 = mfma16(k1, qf[kk], s1);
    }
    float sv[8];
#pragma unroll
    for (int r = 0; r < 4; ++r) { sv[r] = s0[r]; sv[4 + r] = s1[r]; }
    if (kv0 + 31 > qr) {  // wave-uniform: diagonal or fully-masked tiles
#pragma unroll
      for (int f = 0; f < 2; ++f)
#pragma unroll
        for (int r = 0; r < 4; ++r) {
          int kvg = kv0 + f * 16 + lg * 4 + r;
          if (kvg > qr + lc) sv[f * 4 + r] = -1e30f;
        }
    }
    // row max: 7 in-lane + 2 shfl for all 16 rows at once
    float m8 = fmaxf(fmaxf(fmaxf(sv[0], sv[1]), fmaxf(sv[2], sv[3])),
                     fmaxf(fmaxf(sv[4], sv[5]), fmaxf(sv[6], sv[7])));
    float pm = fmaxf(m8, __shfl_xor(m8, 16));
    pm = fmaxf(pm, __shfl_xor(pm, 32));
    // exact defer-max: rescale only if some row's max grew
    if (__ballot(pm > mrow)) {
      float mn = fmaxf(mrow, pm);
      float alpha = __builtin_amdgcn_exp2f(mrow - mn);
      lrow *= alpha;
      float aa[4];
#pragma unroll
      for (int r = 0; r < 4; ++r) aa[r] = __shfl(alpha, lg * 4 + r);
#pragma unroll
      for (int nf = 0; nf < 16; ++nf) {
        f32x4 t4 = o[nf];
#pragma unroll
        for (int r = 0; r < 4; ++r) t4[r] *= aa[r];
        o[nf] = t4;
      }
      mrow = mn;
    }
    float p[8];
#pragma unroll
    for (int j = 0; j < 8; ++j) p[j] = __builtin_amdgcn_exp2f(sv[j] - mrow);
    float ps = ((p[0] + p[1]) + (p[2] + p[3])) + ((p[4] + p[5]) + (p[6] + p[7]));
    ps += __shfl_xor(ps, 16);
    ps += __shfl_xor(ps, 32);
    lrow += ps;
    // P[q=lc][kv] -> per-wave LDS (same-wave DS ops in-order; compiler fence)
    asm volatile("" ::: "memory");
    Pw[lc * 20 + lg * 2 + 0] = cvtpk_bf16(p[0], p[1]);
    Pw[lc * 20 + lg * 2 + 1] = cvtpk_bf16(p[2], p[3]);
    Pw[lc * 20 + 8 + lg * 2 + 0] = cvtpk_bf16(p[4], p[5]);
    Pw[lc * 20 + 8 + lg * 2 + 1] = cvtpk_bf16(p[6], p[7]);
    asm volatile("" ::: "memory");
    short8 pf = *(const short8*)&Pm[lc * 40 + lg * 8];  // row q=lc, kv=lg*8..+7
    // PV from LDS V (swizzled read)
#pragma unroll
    for (int nf = 0; nf < 16; ++nf) {
      const int d = nf * 16 + lc;
      short8 vf = *(const short8*)(VsB + d * 64 + ((lg * 16) ^ (((d >> 1) & 3) << 4)));
      o[nf] = mfma16(pf, vf, o[nf]);  // D[q][d]: q = lg*4+r, d = nf*16+lc
    }
    asm volatile("" ::: "memory");
    __syncthreads();  // drains stage loads (buf^1 ready) + all waves done with buf
  }

  float il = 1.0f / lrow;
  float ia[4];
#pragma unroll
  for (int r = 0; r < 4; ++r) ia[r] = __shfl(il, lg * 4 + r);
  const int crow0 = (bh >> 4) * 2048 + qr;
  const int ccol0 = (bh & 15) * 256;
#pragma unroll
  for (int nf = 0; nf < 16; ++nf)
#pragma unroll
    for (int r = 0; r < 4; ++r)
      ctx[(size_t)(crow0 + lg * 4 + r) * 4096 + ccol0 + nf * 16 + lc] =
          f2bf(o[nf][r] * ia[r]);
}

// ---------- launcher ----------
extern "C" void kernel_launch(void* const* d_in, const int* in_sizes, int n_in,
                              void* d_out, int out_size, void* d_ws, size_t ws_size,
                              hipStream_t stream) {
  const float* hidden = (const float*)d_in[0];
  const float* Wq = (const float*)d_in[1];
  const float* Wk = (const float*)d_in[2];
  const float* Wv = (const float*)d_in[3];
  const float* Wo = (const float*)d_in[4];
  const int* pos = (const int*)d_in[5];

  const size_t NEL = 16777216;  // 4096*4096
  if (ws_size < 6 * NEL * sizeof(u16)) return;  // need 192 MB scratch

  u16* hb = (u16*)d_ws;      // hidden bf16; reused as ctx after QKV GEMMs
  u16* wq = hb + NEL;
  u16* wk = wq + NEL;
  u16* wv = wk + NEL;
  u16* wo = wv + NEL;
  u16* vt = wo + NEL;        // V^T [bh][d][s]
  u16* ctx = hb;
  u16* qb = (u16*)d_out;     // Q,K live in d_out (exactly 64MB); overwritten by final GEMM
  u16* kb = qb + NEL;

  cvt_bf16<<<8192, 256, 0, stream>>>(hidden, hb);
  cvt_bf16<<<8192, 256, 0, stream>>>(Wq, wq);
  cvt_bf16<<<8192, 256, 0, stream>>>(Wk, wk);
  cvt_bf16<<<8192, 256, 0, stream>>>(Wv, wv);
  cvt_bf16<<<8192, 256, 0, stream>>>(Wo, wo);

  dim3 gg(32, 32);
  // Q pre-scaled by log2(e)/16 so flash softmax runs in exp2 domain.
  gemm_nt<0><<<gg, 256, 0, stream>>>(hb, wq, qb, 0.09016844f);
  gemm_nt<0><<<gg, 256, 0, stream>>>(hb, wk, kb, 1.0f);
  gemm_nt<1><<<gg, 256, 0, stream>>>(hb, wv, vt, 1.0f);

  rope_qk<<<16384, 256, 0, stream>>>(qb, kb, pos);

  flash_attn<<<1024, 256, 0, stream>>>(qb, kb, vt, ctx);

  gemm_nt<2><<<gg, 256, 0, stream>>>(ctx, wo, d_out, 1.0f);
}

// Round 4
// 996.790 us; speedup vs baseline: 2.0930x; 1.1405x over previous
//
#include <hip/hip_runtime.h>
#include <stdint.h>

// ---------- types ----------
typedef unsigned short u16;
typedef short short8 __attribute__((ext_vector_type(8)));
typedef __bf16 bf16x8 __attribute__((ext_vector_type(8)));
typedef float f32x4 __attribute__((ext_vector_type(4)));

__device__ __forceinline__ u16 f2bf(float f) {
  uint32_t u = __float_as_uint(f);
  u += 0x7fffu + ((u >> 16) & 1u);   // RNE
  return (u16)(u >> 16);
}
__device__ __forceinline__ float bf2f(u16 h) {
  return __uint_as_float(((uint32_t)h) << 16);
}
__device__ __forceinline__ f32x4 mfma16(short8 a, short8 b, f32x4 c) {
  return __builtin_amdgcn_mfma_f32_16x16x32_bf16(
      __builtin_bit_cast(bf16x8, a), __builtin_bit_cast(bf16x8, b), c, 0, 0, 0);
}
__device__ __forceinline__ uint32_t cvtpk_bf16(float lo, float hi) {
  uint32_t r;
  asm("v_cvt_pk_bf16_f32 %0, %1, %2" : "=v"(r) : "v"(lo), "v"(hi));
  return r;
}
// async global->LDS, 16B per lane; LDS dest must be the wave-uniform base.
__device__ __forceinline__ void gld_lds16(const u16* g, u16* lds_base) {
  __builtin_amdgcn_global_load_lds(
      (__attribute__((address_space(1))) void*)g,
      (__attribute__((address_space(3))) void*)lds_base, 16, 0, 0);
}
// raw barrier with compiler-only memory fence (no vmcnt/lgkmcnt drain!)
#define BAR() do { asm volatile("" ::: "memory"); \
                   __builtin_amdgcn_s_barrier(); \
                   asm volatile("" ::: "memory"); } while (0)

// ---------- fp32 -> bf16 convert (8 elem/thread) ----------
__global__ __launch_bounds__(256) void cvt_bf16(const float* __restrict__ s,
                                                u16* __restrict__ d) {
  int i = blockIdx.x * 256 + threadIdx.x;
  const float4* s4 = (const float4*)s;
  float4 a = s4[2 * i], b = s4[2 * i + 1];
  uint4 o;
  o.x = (uint32_t)f2bf(a.x) | ((uint32_t)f2bf(a.y) << 16);
  o.y = (uint32_t)f2bf(a.z) | ((uint32_t)f2bf(a.w) << 16);
  o.z = (uint32_t)f2bf(b.x) | ((uint32_t)f2bf(b.y) << 16);
  o.w = (uint32_t)f2bf(b.z) | ((uint32_t)f2bf(b.w) << 16);
  ((uint4*)d)[i] = o;
}

// ---------- NT GEMM, 256x256 8-phase counted-vmcnt (m201-style) ----------
// C[4096x4096] = A * W^T. 8 waves (2M x 4N), per-wave 128x64 out, BK=64.
// LDS: 8 units x 16KB. A-unit h = rows {wm*128 + h*64 + i} (quadrant mq=h);
// B-unit h = rows {wn*64 + h*32 + i} (quadrant nq=h). Unit layout: row_local
// rl (A: wm*64+i, B: wn*32+i) at rl*128B; 16B slot s holds global k-slot
// s^(rl&7) (swizzle on stage source + ds_read => conflict-free b128).
// Phase p of K-tile t: quadrant Gray order (0,0),(0,1),(1,1),(1,0); stages:
// p0:B0(t+1) p1:A1(t+1) p2:A0(t+2) p3:B1(t+2); vmcnt(4) before p3's closing
// barrier retires all of K-tile t+1 block-wide (2 units stay in flight).
// MODE 0: bf16 out [(b*16+h)][s][d]; MODE 1: bf16 out [(b*16+h)][d][s];
// MODE 2: fp32 out row-major.
template <int MODE>
__global__ __launch_bounds__(512, 2) void gemm_nt(const u16* __restrict__ A,
                                                  const u16* __restrict__ W,
                                                  void* __restrict__ outp,
                                                  float oscale) {
  constexpr int Kd = 4096;
  __shared__ __align__(16) u16 As[2][2][8192];
  __shared__ __align__(16) u16 Bs[2][2][8192];
  const int tid = threadIdx.x;
  const int wid = tid >> 6, l = tid & 63;
  const int lg = (l >> 4) & 3, lc = l & 15;
  const int wm = wid >> 2, wn = wid & 3;  // 2 x 4 wave grid
  // XCD swizzle: 256 blocks % 8 == 0 -> bijective; 32-block chunks per XCD.
  const int bid0 = blockIdx.x;
  const int bid = (bid0 & 7) * 32 + (bid0 >> 3);
  const int m0 = (bid >> 4) * 256, n0 = (bid & 15) * 256;

  // staging per-thread constants (each unit: 2 calls x 512 thr x 16B = 16KB)
  const int srow = tid >> 3;                    // 0..63
  const int scol = ((tid & 7) ^ (srow & 7)) * 8;  // swizzled k-slot source, u16
  const int arow = m0 + srow;                   // + c*128 + h*64
  const int browb = n0 + ((srow >> 5) & 1) * 64 + (srow & 31);  // + c*128 + h*32

#define STAGE_A(BUF, H, T) do { \
    const u16* g0 = A + (size_t)(arow + (H) * 64) * Kd + (T) * 64 + scol; \
    gld_lds16(g0, &As[BUF][H][wid * 512]); \
    gld_lds16(g0 + (size_t)128 * Kd, &As[BUF][H][4096 + wid * 512]); \
  } while (0)
#define STAGE_B(BUF, H, T) do { \
    const u16* g0 = W + (size_t)(browb + (H) * 32) * Kd + (T) * 64 + scol; \
    gld_lds16(g0, &Bs[BUF][H][wid * 512]); \
    gld_lds16(g0 + (size_t)128 * Kd, &Bs[BUF][H][4096 + wid * 512]); \
  } while (0)

  f32x4 acc[8][4];
#pragma unroll
  for (int i = 0; i < 8; ++i)
#pragma unroll
    for (int j = 0; j < 4; ++j) acc[i][j] = (f32x4)0.0f;

  const int axor = (lc & 7);  // row_local&7 for all fragment rows (=lc&7)

#define PHASE(MQ, NQ, STAGES, WAITV) do { \
    short8 af_[4][2], bf_[2][2]; \
    const char* Ab_ = (const char*)As[buf][MQ] + (wm * 64 + lc) * 128; \
    const char* Bb_ = (const char*)Bs[buf][NQ] + (wn * 32 + lc) * 128; \
    _Pragma("unroll") for (int f = 0; f < 4; ++f) \
      _Pragma("unroll") for (int kk = 0; kk < 2; ++kk) \
        af_[f][kk] = *(const short8*)(Ab_ + f * 2048 + (((kk * 4 + lg) ^ axor) << 4)); \
    _Pragma("unroll") for (int g = 0; g < 2; ++g) \
      _Pragma("unroll") for (int kk = 0; kk < 2; ++kk) \
        bf_[g][kk] = *(const short8*)(Bb_ + g * 2048 + (((kk * 4 + lg) ^ axor) << 4)); \
    STAGES; \
    WAITV; \
    BAR(); \
    __builtin_amdgcn_s_setprio(1); \
    _Pragma("unroll") for (int f = 0; f < 4; ++f) \
      _Pragma("unroll") for (int g = 0; g < 2; ++g) \
        _Pragma("unroll") for (int kk = 0; kk < 2; ++kk) \
          acc[(MQ) * 4 + f][(NQ) * 2 + g] = \
              mfma16(af_[f][kk], bf_[g][kk], acc[(MQ) * 4 + f][(NQ) * 2 + g]); \
    __builtin_amdgcn_s_setprio(0); \
    BAR(); \
  } while (0)

  // prologue: issue K0 units (oldest 4) + A0(1),B1(1); retire K0; barrier.
  STAGE_A(0, 0, 0); STAGE_B(0, 1, 0); STAGE_B(0, 0, 0); STAGE_A(0, 1, 0);
  STAGE_A(1, 0, 1); STAGE_B(1, 1, 1);
  asm volatile("s_waitcnt vmcnt(4)" ::: "memory");
  BAR();

#pragma unroll 1
  for (int t = 0; t < 62; ++t) {
    const int buf = t & 1, nbuf = buf ^ 1;
    PHASE(0, 0, STAGE_B(nbuf, 0, t + 1), (void)0);
    PHASE(0, 1, STAGE_A(nbuf, 1, t + 1), (void)0);
    PHASE(1, 1, STAGE_A(buf, 0, t + 2), (void)0);
    PHASE(1, 0, STAGE_B(buf, 1, t + 2),
          asm volatile("s_waitcnt vmcnt(4)" ::: "memory"));
  }
  {  // t = 62: stage only K-tile 63's remaining units; drain.
    const int buf = 0, nbuf = 1;
    PHASE(0, 0, STAGE_B(nbuf, 0, 63), (void)0);
    PHASE(0, 1, STAGE_A(nbuf, 1, 63), (void)0);
    PHASE(1, 1, (void)0, (void)0);
    PHASE(1, 0, (void)0, asm volatile("s_waitcnt vmcnt(0)" ::: "memory"));
  }
  {  // t = 63: no staging.
    const int buf = 1;
    PHASE(0, 0, (void)0, (void)0);
    PHASE(0, 1, (void)0, (void)0);
    PHASE(1, 1, (void)0, (void)0);
    PHASE(1, 0, (void)0, (void)0);
  }
#undef PHASE
#undef STAGE_A
#undef STAGE_B

  const int gr0 = m0 + wm * 128, gc0 = n0 + wn * 64;
#pragma unroll
  for (int mf = 0; mf < 8; ++mf)
#pragma unroll
    for (int nf = 0; nf < 4; ++nf)
#pragma unroll
      for (int r = 0; r < 4; ++r) {
        float v = acc[mf][nf][r] * oscale;
        int gr = gr0 + mf * 16 + lg * 4 + r;  // m index
        int gc = gc0 + nf * 16 + lc;          // n index
        if constexpr (MODE == 0) {
          ((u16*)outp)[((size_t)(((gr >> 11) * 16 + (gc >> 8)) * 2048 +
                                 (gr & 2047))) * 256 + (gc & 255)] = f2bf(v);
        } else if constexpr (MODE == 1) {
          ((u16*)outp)[(size_t)((gr >> 11) * 4096 + gc) * 2048 + (gr & 2047)] =
              f2bf(v);
        } else {
          ((float*)outp)[(size_t)gr * 4096 + gc] = v;
        }
      }
}

// ---------- GPT-J interleaved RoPE on Q,K (first 64 dims/head), in place ----------
__global__ __launch_bounds__(256) void rope_qk(u16* __restrict__ Qb,
                                               u16* __restrict__ Kb,
                                               const int* __restrict__ pos) {
  int idx = blockIdx.x * 256 + threadIdx.x;  // [2][32 bh][2048 s][32 pairs]
  int pair = idx & 31;
  int s = (idx >> 5) & 2047;
  int bh = (idx >> 16) & 31;
  u16* T = (idx >> 21) ? Kb : Qb;
  float p = (float)pos[s];
  float inv = powf(10000.0f, -(float)pair * (1.0f / 32.0f));
  float ang = p * inv, sn, cs;
  sincosf(ang, &sn, &cs);
  u16* base = T + ((size_t)bh * 2048 + s) * 256 + pair * 2;
  float x1 = bf2f(base[0]), x2 = bf2f(base[1]);
  base[0] = f2bf(x1 * cs - x2 * sn);
  base[1] = f2bf(x2 * cs + x1 * sn);
}

// ---------- causal flash attention (verified R3 version) ----------
__global__ __launch_bounds__(256) void flash_attn(const u16* __restrict__ Q,
                                                  const u16* __restrict__ K,
                                                  const u16* __restrict__ Vt,
                                                  u16* __restrict__ ctx) {
  __shared__ u16 Ks[2][32 * 256];
  __shared__ u16 Vs[2][256 * 32];
  __shared__ u16 P[4][16 * 40];

  const int bid = blockIdx.x;
  const int bidp = (bid & 7) * 128 + (bid >> 3);
  const int bh = bidp >> 5;
  const int qi = bidp & 31;
  const int q0 = 1984 - qi * 64;
  const int tid = threadIdx.x;
  const int wid = tid >> 6, l = tid & 63;
  const int lg = l >> 4, lc = l & 15;
  const int qr = q0 + wid * 16;

  const u16* Qh = Q + (size_t)bh * 2048 * 256;
  const u16* Kh = K + (size_t)bh * 2048 * 256;
  const u16* Vh = Vt + (size_t)bh * 256 * 2048;

  int krow[4], kcol[4], vrow[4], vcol[4];
#pragma unroll
  for (int jj = 0; jj < 4; ++jj) {
    int j = wid * 4 + jj;
    krow[jj] = 2 * j + (l >> 5);
    kcol[jj] = ((((l & 31) << 4) ^ ((krow[jj] & 7) << 4)) >> 1);
    vrow[jj] = j * 16 + (l >> 2);
    vcol[jj] = ((((l & 3) << 4) ^ (((vrow[jj] >> 1) & 3) << 4)) >> 1);
  }

  short8 qf[8];
#pragma unroll
  for (int kk = 0; kk < 8; ++kk)
    qf[kk] = *(const short8*)&Qh[(size_t)(qr + lc) * 256 + kk * 32 + lg * 8];

  f32x4 o[16];
#pragma unroll
  for (int nf = 0; nf < 16; ++nf) o[nf] = (f32x4)0.0f;
  float mrow = -1e30f;
  float lrow = 0.0f;

  uint32_t* Pw = (uint32_t*)P[wid];
  const u16* Pm = P[wid];

  const int ntiles = q0 / 32 + 2;

#pragma unroll
  for (int jj = 0; jj < 4; ++jj) {
    gld_lds16(Kh + (size_t)krow[jj] * 256 + kcol[jj], &Ks[0][(wid * 4 + jj) * 512]);
    gld_lds16(Vh + (size_t)vrow[jj] * 2048 + vcol[jj], &Vs[0][(wid * 4 + jj) * 512]);
  }
  __syncthreads();

  for (int t = 0; t < ntiles; ++t) {
    const int buf = t & 1;
    if (t + 1 < ntiles) {
      const int kv1 = (t + 1) << 5;
#pragma unroll
      for (int jj = 0; jj < 4; ++jj) {
        gld_lds16(Kh + (size_t)(kv1 + krow[jj]) * 256 + kcol[jj],
                  &Ks[buf ^ 1][(wid * 4 + jj) * 512]);
        gld_lds16(Vh + (size_t)vrow[jj] * 2048 + kv1 + vcol[jj],
                  &Vs[buf ^ 1][(wid * 4 + jj) * 512]);
      }
    }
    const int kv0 = t << 5;
    const char* KsB = (const char*)Ks[buf];
    const char* VsB = (const char*)Vs[buf];

    f32x4 s0 = (f32x4)0.0f, s1 = (f32x4)0.0f;
#pragma unroll
    for (int kk = 0; kk < 8; ++kk) {
      const int cb = kk * 64 + lg * 16;
      short8 k0 = *(const short8*)(KsB + lc * 512 + (cb ^ ((lc & 7) << 4)));
      short8 k1 = *(const short8*)(KsB + (16 + lc) * 512 + (cb ^ ((lc & 7) << 4)));
      s0 = mfma16(k0, qf[kk], s0);
      s1 = mfma16(k1, qf[kk], s1);
    }
    float sv[8];
#pragma unroll
    for (int r = 0; r < 4; ++r) { sv[r] = s0[r]; sv[4 + r] = s1[r]; }
    if (kv0 + 31 > qr) {
#pragma unroll
      for (int f = 0; f < 2; ++f)
#pragma unroll
        for (int r = 0; r < 4; ++r) {
          int kvg = kv0 + f * 16 + lg * 4 + r;
          if (kvg > qr + lc) sv[f * 4 + r] = -1e30f;
        }
    }
    float m8 = fmaxf(fmaxf(fmaxf(sv[0], sv[1]), fmaxf(sv[2], sv[3])),
                     fmaxf(fmaxf(sv[4], sv[5]), fmaxf(sv[6], sv[7])));
    float pm = fmaxf(m8, __shfl_xor(m8, 16));
    pm = fmaxf(pm, __shfl_xor(pm, 32));
    if (__ballot(pm > mrow)) {
      float mn = fmaxf(mrow, pm);
      float alpha = __builtin_amdgcn_exp2f(mrow - mn);
      lrow *= alpha;
      float aa[4];
#pragma unroll
      for (int r = 0; r < 4; ++r) aa[r] = __shfl(alpha, lg * 4 + r);
#pragma unroll
      for (int nf = 0; nf < 16; ++nf) {
        f32x4 t4 = o[nf];
#pragma unroll
        for (int r = 0; r < 4; ++r) t4[r] *= aa[r];
        o[nf] = t4;
      }
      mrow = mn;
    }
    float p[8];
#pragma unroll
    for (int j = 0; j < 8; ++j) p[j] = __builtin_amdgcn_exp2f(sv[j] - mrow);
    float ps = ((p[0] + p[1]) + (p[2] + p[3])) + ((p[4] + p[5]) + (p[6] + p[7]));
    ps += __shfl_xor(ps, 16);
    ps += __shfl_xor(ps, 32);
    lrow += ps;
    asm volatile("" ::: "memory");
    Pw[lc * 20 + lg * 2 + 0] = cvtpk_bf16(p[0], p[1]);
    Pw[lc * 20 + lg * 2 + 1] = cvtpk_bf16(p[2], p[3]);
    Pw[lc * 20 + 8 + lg * 2 + 0] = cvtpk_bf16(p[4], p[5]);
    Pw[lc * 20 + 8 + lg * 2 + 1] = cvtpk_bf16(p[6], p[7]);
    asm volatile("" ::: "memory");
    short8 pf = *(const short8*)&Pm[lc * 40 + lg * 8];
#pragma unroll
    for (int nf = 0; nf < 16; ++nf) {
      const int d = nf * 16 + lc;
      short8 vf = *(const short8*)(VsB + d * 64 + ((lg * 16) ^ (((d >> 1) & 3) << 4)));
      o[nf] = mfma16(pf, vf, o[nf]);
    }
    asm volatile("" ::: "memory");
    __syncthreads();
  }

  float il = 1.0f / lrow;
  float ia[4];
#pragma unroll
  for (int r = 0; r < 4; ++r) ia[r] = __shfl(il, lg * 4 + r);
  const int crow0 = (bh >> 4) * 2048 + qr;
  const int ccol0 = (bh & 15) * 256;
#pragma unroll
  for (int nf = 0; nf < 16; ++nf)
#pragma unroll
    for (int r = 0; r < 4; ++r)
      ctx[(size_t)(crow0 + lg * 4 + r) * 4096 + ccol0 + nf * 16 + lc] =
          f2bf(o[nf][r] * ia[r]);
}

// ---------- launcher ----------
extern "C" void kernel_launch(void* const* d_in, const int* in_sizes, int n_in,
                              void* d_out, int out_size, void* d_ws, size_t ws_size,
                              hipStream_t stream) {
  const float* hidden = (const float*)d_in[0];
  const float* Wq = (const float*)d_in[1];
  const float* Wk = (const float*)d_in[2];
  const float* Wv = (const float*)d_in[3];
  const float* Wo = (const float*)d_in[4];
  const int* pos = (const int*)d_in[5];

  const size_t NEL = 16777216;  // 4096*4096
  if (ws_size < 6 * NEL * sizeof(u16)) return;  // need 192 MB scratch

  u16* hb = (u16*)d_ws;      // hidden bf16; reused as ctx after QKV GEMMs
  u16* wq = hb + NEL;
  u16* wk = wq + NEL;
  u16* wv = wk + NEL;
  u16* wo = wv + NEL;
  u16* vt = wo + NEL;        // V^T [bh][d][s]
  u16* ctx = hb;
  u16* qb = (u16*)d_out;     // Q,K live in d_out; overwritten by final GEMM
  u16* kb = qb + NEL;

  cvt_bf16<<<8192, 256, 0, stream>>>(hidden, hb);
  cvt_bf16<<<8192, 256, 0, stream>>>(Wq, wq);
  cvt_bf16<<<8192, 256, 0, stream>>>(Wk, wk);
  cvt_bf16<<<8192, 256, 0, stream>>>(Wv, wv);
  cvt_bf16<<<8192, 256, 0, stream>>>(Wo, wo);

  // Q pre-scaled by log2(e)/16 so flash softmax runs in exp2 domain.
  gemm_nt<0><<<256, 512, 0, stream>>>(hb, wq, qb, 0.09016844f);
  gemm_nt<0><<<256, 512, 0, stream>>>(hb, wk, kb, 1.0f);
  gemm_nt<1><<<256, 512, 0, stream>>>(hb, wv, vt, 1.0f);

  rope_qk<<<16384, 256, 0, stream>>>(qb, kb, pos);

  flash_attn<<<1024, 256, 0, stream>>>(qb, kb, vt, ctx);

  gemm_nt<2><<<256, 512, 0, stream>>>(ctx, wo, d_out, 1.0f);
}

// Round 5
// 872.357 us; speedup vs baseline: 2.3915x; 1.1426x over previous
//
#include <hip/hip_runtime.h>
#include <stdint.h>

// ---------- types ----------
typedef unsigned short u16;
typedef short short8 __attribute__((ext_vector_type(8)));
typedef __bf16 bf16x8 __attribute__((ext_vector_type(8)));
typedef float f32x4 __attribute__((ext_vector_type(4)));

__device__ __forceinline__ u16 f2bf(float f) {
  uint32_t u = __float_as_uint(f);
  u += 0x7fffu + ((u >> 16) & 1u);   // RNE
  return (u16)(u >> 16);
}
__device__ __forceinline__ float bf2f(u16 h) {
  return __uint_as_float(((uint32_t)h) << 16);
}
__device__ __forceinline__ f32x4 mfma16(short8 a, short8 b, f32x4 c) {
  return __builtin_amdgcn_mfma_f32_16x16x32_bf16(
      __builtin_bit_cast(bf16x8, a), __builtin_bit_cast(bf16x8, b), c, 0, 0, 0);
}
__device__ __forceinline__ uint32_t cvtpk_bf16(float lo, float hi) {
  uint32_t r;
  asm("v_cvt_pk_bf16_f32 %0, %1, %2" : "=v"(r) : "v"(lo), "v"(hi));
  return r;
}
// async global->LDS, 16B per lane; LDS dest must be the wave-uniform base.
__device__ __forceinline__ void gld_lds16(const u16* g, u16* lds_base) {
  __builtin_amdgcn_global_load_lds(
      (__attribute__((address_space(1))) void*)g,
      (__attribute__((address_space(3))) void*)lds_base, 16, 0, 0);
}
// raw barrier with compiler-only memory fence (no vmcnt/lgkmcnt drain!)
#define BAR() do { asm volatile("" ::: "memory"); \
                   __builtin_amdgcn_s_barrier(); \
                   asm volatile("" ::: "memory"); } while (0)

// ---------- fp32 -> bf16 convert (8 elem/thread) ----------
__global__ __launch_bounds__(256) void cvt_bf16(const float* __restrict__ s,
                                                u16* __restrict__ d) {
  int i = blockIdx.x * 256 + threadIdx.x;
  const float4* s4 = (const float4*)s;
  float4 a = s4[2 * i], b = s4[2 * i + 1];
  uint4 o;
  o.x = (uint32_t)f2bf(a.x) | ((uint32_t)f2bf(a.y) << 16);
  o.y = (uint32_t)f2bf(a.z) | ((uint32_t)f2bf(a.w) << 16);
  o.z = (uint32_t)f2bf(b.x) | ((uint32_t)f2bf(b.y) << 16);
  o.w = (uint32_t)f2bf(b.z) | ((uint32_t)f2bf(b.w) << 16);
  ((uint4*)d)[i] = o;
}

// ---------- NT GEMM, 256x256 8-phase counted-vmcnt, register-held frags ----------
// C[4096x4096] = A * W^T. 8 waves (2M x 4N), per-wave 128x64 out, BK=64.
// LDS: 8 units x 16KB, layout/swizzle identical to R4 (0 bank conflicts).
// Gray-ordered quadrants with REGISTER REUSE (m201's "4 or 8 ds_read/phase"):
//   p0 (0,0): read A0(8)+B0(4); stage B0(t+1)->nbuf
//   p1 (0,1): read B1(4)        [A held]; stage A1(t+1)->nbuf
//   p2 (1,1): read A1(8)        [B1 held]; stage A0(t+2)->buf
//   p3 (1,0): no reads          [A1,B0 held]; stage B1(t+2)->buf; vmcnt(4)
// 24 ds_read_b128/wave/K-tile (was 48 -> LDS-pipe-bound at MfmaUtil 26%).
// Unit lifetimes vs stage schedule: A0[buf] last read p0, staged-over p2; B1[buf]
// last read p1, staged-over p3; B0[buf] read p0 only (regs thereafter). vmcnt(4)
// at p3 retires all 4 units of K-tile t+1 block-wide; 2 units stay in flight.
template <int MODE>
__global__ __launch_bounds__(512, 2) void gemm_nt(const u16* __restrict__ A,
                                                  const u16* __restrict__ W,
                                                  void* __restrict__ outp,
                                                  float oscale) {
  constexpr int Kd = 4096;
  __shared__ __align__(16) u16 As[2][2][8192];
  __shared__ __align__(16) u16 Bs[2][2][8192];
  const int tid = threadIdx.x;
  const int wid = tid >> 6, l = tid & 63;
  const int lg = (l >> 4) & 3, lc = l & 15;
  const int wm = wid >> 2, wn = wid & 3;  // 2 x 4 wave grid
  // XCD swizzle: 256 blocks % 8 == 0 -> bijective; 32-block chunks per XCD.
  const int bid0 = blockIdx.x;
  const int bid = (bid0 & 7) * 32 + (bid0 >> 3);
  const int m0 = (bid >> 4) * 256, n0 = (bid & 15) * 256;

  // staging per-thread constants (each unit: 2 calls x 512 thr x 16B = 16KB)
  const int srow = tid >> 3;                    // 0..63
  const int scol = ((tid & 7) ^ (srow & 7)) * 8;  // swizzled k-slot source, u16
  const int arow = m0 + srow;                   // + c*128 + h*64
  const int browb = n0 + ((srow >> 5) & 1) * 64 + (srow & 31);  // + c*128 + h*32

#define STAGE_A(BUF, H, T) do { \
    const u16* g0 = A + (size_t)(arow + (H) * 64) * Kd + (T) * 64 + scol; \
    gld_lds16(g0, &As[BUF][H][wid * 512]); \
    gld_lds16(g0 + (size_t)128 * Kd, &As[BUF][H][4096 + wid * 512]); \
  } while (0)
#define STAGE_B(BUF, H, T) do { \
    const u16* g0 = W + (size_t)(browb + (H) * 32) * Kd + (T) * 64 + scol; \
    gld_lds16(g0, &Bs[BUF][H][wid * 512]); \
    gld_lds16(g0 + (size_t)128 * Kd, &Bs[BUF][H][4096 + wid * 512]); \
  } while (0)

  f32x4 acc[8][4];
#pragma unroll
  for (int i = 0; i < 8; ++i)
#pragma unroll
    for (int j = 0; j < 4; ++j) acc[i][j] = (f32x4)0.0f;

  const int axor = (lc & 7);

  short8 af[4][2], b0f[2][2], b1f[2][2];

#define LDA(MQ) do { \
    const char* Ab_ = (const char*)As[buf][MQ] + (wm * 64 + lc) * 128; \
    _Pragma("unroll") for (int f = 0; f < 4; ++f) \
      _Pragma("unroll") for (int kk = 0; kk < 2; ++kk) \
        af[f][kk] = *(const short8*)(Ab_ + f * 2048 + (((kk * 4 + lg) ^ axor) << 4)); \
  } while (0)
#define LDB(DST, NQ) do { \
    const char* Bb_ = (const char*)Bs[buf][NQ] + (wn * 32 + lc) * 128; \
    _Pragma("unroll") for (int g = 0; g < 2; ++g) \
      _Pragma("unroll") for (int kk = 0; kk < 2; ++kk) \
        DST[g][kk] = *(const short8*)(Bb_ + g * 2048 + (((kk * 4 + lg) ^ axor) << 4)); \
  } while (0)
#define MM(MQ, NQ, BF) do { \
    __builtin_amdgcn_s_setprio(1); \
    _Pragma("unroll") for (int f = 0; f < 4; ++f) \
      _Pragma("unroll") for (int g = 0; g < 2; ++g) \
        _Pragma("unroll") for (int kk = 0; kk < 2; ++kk) \
          acc[(MQ) * 4 + f][(NQ) * 2 + g] = \
              mfma16(af[f][kk], BF[g][kk], acc[(MQ) * 4 + f][(NQ) * 2 + g]); \
    __builtin_amdgcn_s_setprio(0); \
  } while (0)

  // prologue: issue K0 units (oldest 4) + A0(1),B1(1); retire K0; barrier.
  STAGE_A(0, 0, 0); STAGE_B(0, 1, 0); STAGE_B(0, 0, 0); STAGE_A(0, 1, 0);
  STAGE_A(1, 0, 1); STAGE_B(1, 1, 1);
  asm volatile("s_waitcnt vmcnt(4)" ::: "memory");
  BAR();

#pragma unroll 1
  for (int t = 0; t < 62; ++t) {
    const int buf = t & 1, nbuf = buf ^ 1;
    LDA(0); LDB(b0f, 0); STAGE_B(nbuf, 0, t + 1);
    BAR(); MM(0, 0, b0f); BAR();
    LDB(b1f, 1); STAGE_A(nbuf, 1, t + 1);
    BAR(); MM(0, 1, b1f); BAR();
    LDA(1); STAGE_A(buf, 0, t + 2);
    BAR(); MM(1, 1, b1f); BAR();
    STAGE_B(buf, 1, t + 2);
    asm volatile("s_waitcnt vmcnt(4)" ::: "memory");
    BAR(); MM(1, 0, b0f); BAR();
  }
  {  // t = 62: stage only K-tile 63's remaining units; drain.
    const int buf = 0, nbuf = 1;
    LDA(0); LDB(b0f, 0); STAGE_B(nbuf, 0, 63);
    BAR(); MM(0, 0, b0f); BAR();
    LDB(b1f, 1); STAGE_A(nbuf, 1, 63);
    BAR(); MM(0, 1, b1f); BAR();
    LDA(1);
    BAR(); MM(1, 1, b1f); BAR();
    asm volatile("s_waitcnt vmcnt(0)" ::: "memory");
    BAR(); MM(1, 0, b0f); BAR();
  }
  {  // t = 63: no staging.
    const int buf = 1;
    LDA(0); LDB(b0f, 0);
    BAR(); MM(0, 0, b0f); BAR();
    LDB(b1f, 1);
    BAR(); MM(0, 1, b1f); BAR();
    LDA(1);
    BAR(); MM(1, 1, b1f); BAR();
    BAR(); MM(1, 0, b0f); BAR();
  }
#undef MM
#undef LDB
#undef LDA
#undef STAGE_A
#undef STAGE_B

  const int gr0 = m0 + wm * 128, gc0 = n0 + wn * 64;
#pragma unroll
  for (int mf = 0; mf < 8; ++mf)
#pragma unroll
    for (int nf = 0; nf < 4; ++nf)
#pragma unroll
      for (int r = 0; r < 4; ++r) {
        float v = acc[mf][nf][r] * oscale;
        int gr = gr0 + mf * 16 + lg * 4 + r;  // m index
        int gc = gc0 + nf * 16 + lc;          // n index
        if constexpr (MODE == 0) {
          ((u16*)outp)[((size_t)(((gr >> 11) * 16 + (gc >> 8)) * 2048 +
                                 (gr & 2047))) * 256 + (gc & 255)] = f2bf(v);
        } else if constexpr (MODE == 1) {
          ((u16*)outp)[(size_t)((gr >> 11) * 4096 + gc) * 2048 + (gr & 2047)] =
              f2bf(v);
        } else {
          ((float*)outp)[(size_t)gr * 4096 + gc] = v;
        }
      }
}

// ---------- GPT-J interleaved RoPE on Q,K (first 64 dims/head), in place ----------
__global__ __launch_bounds__(256) void rope_qk(u16* __restrict__ Qb,
                                               u16* __restrict__ Kb,
                                               const int* __restrict__ pos) {
  int idx = blockIdx.x * 256 + threadIdx.x;  // [2][32 bh][2048 s][32 pairs]
  int pair = idx & 31;
  int s = (idx >> 5) & 2047;
  int bh = (idx >> 16) & 31;
  u16* T = (idx >> 21) ? Kb : Qb;
  float p = (float)pos[s];
  float inv = powf(10000.0f, -(float)pair * (1.0f / 32.0f));
  float ang = p * inv, sn, cs;
  sincosf(ang, &sn, &cs);
  u16* base = T + ((size_t)bh * 2048 + s) * 256 + pair * 2;
  float x1 = bf2f(base[0]), x2 = bf2f(base[1]);
  base[0] = f2bf(x1 * cs - x2 * sn);
  base[1] = f2bf(x2 * cs + x1 * sn);
}

// ---------- causal flash attention (verified R3/R4 version) ----------
__global__ __launch_bounds__(256) void flash_attn(const u16* __restrict__ Q,
                                                  const u16* __restrict__ K,
                                                  const u16* __restrict__ Vt,
                                                  u16* __restrict__ ctx) {
  __shared__ u16 Ks[2][32 * 256];
  __shared__ u16 Vs[2][256 * 32];
  __shared__ u16 P[4][16 * 40];

  const int bid = blockIdx.x;
  const int bidp = (bid & 7) * 128 + (bid >> 3);
  const int bh = bidp >> 5;
  const int qi = bidp & 31;
  const int q0 = 1984 - qi * 64;
  const int tid = threadIdx.x;
  const int wid = tid >> 6, l = tid & 63;
  const int lg = l >> 4, lc = l & 15;
  const int qr = q0 + wid * 16;

  const u16* Qh = Q + (size_t)bh * 2048 * 256;
  const u16* Kh = K + (size_t)bh * 2048 * 256;
  const u16* Vh = Vt + (size_t)bh * 256 * 2048;

  int krow[4], kcol[4], vrow[4], vcol[4];
#pragma unroll
  for (int jj = 0; jj < 4; ++jj) {
    int j = wid * 4 + jj;
    krow[jj] = 2 * j + (l >> 5);
    kcol[jj] = ((((l & 31) << 4) ^ ((krow[jj] & 7) << 4)) >> 1);
    vrow[jj] = j * 16 + (l >> 2);
    vcol[jj] = ((((l & 3) << 4) ^ (((vrow[jj] >> 1) & 3) << 4)) >> 1);
  }

  short8 qf[8];
#pragma unroll
  for (int kk = 0; kk < 8; ++kk)
    qf[kk] = *(const short8*)&Qh[(size_t)(qr + lc) * 256 + kk * 32 + lg * 8];

  f32x4 o[16];
#pragma unroll
  for (int nf = 0; nf < 16; ++nf) o[nf] = (f32x4)0.0f;
  float mrow = -1e30f;
  float lrow = 0.0f;

  uint32_t* Pw = (uint32_t*)P[wid];
  const u16* Pm = P[wid];

  const int ntiles = q0 / 32 + 2;

#pragma unroll
  for (int jj = 0; jj < 4; ++jj) {
    gld_lds16(Kh + (size_t)krow[jj] * 256 + kcol[jj], &Ks[0][(wid * 4 + jj) * 512]);
    gld_lds16(Vh + (size_t)vrow[jj] * 2048 + vcol[jj], &Vs[0][(wid * 4 + jj) * 512]);
  }
  __syncthreads();

  for (int t = 0; t < ntiles; ++t) {
    const int buf = t & 1;
    if (t + 1 < ntiles) {
      const int kv1 = (t + 1) << 5;
#pragma unroll
      for (int jj = 0; jj < 4; ++jj) {
        gld_lds16(Kh + (size_t)(kv1 + krow[jj]) * 256 + kcol[jj],
                  &Ks[buf ^ 1][(wid * 4 + jj) * 512]);
        gld_lds16(Vh + (size_t)vrow[jj] * 2048 + kv1 + vcol[jj],
                  &Vs[buf ^ 1][(wid * 4 + jj) * 512]);
      }
    }
    const int kv0 = t << 5;
    const char* KsB = (const char*)Ks[buf];
    const char* VsB = (const char*)Vs[buf];

    f32x4 s0 = (f32x4)0.0f, s1 = (f32x4)0.0f;
#pragma unroll
    for (int kk = 0; kk < 8; ++kk) {
      const int cb = kk * 64 + lg * 16;
      short8 k0 = *(const short8*)(KsB + lc * 512 + (cb ^ ((lc & 7) << 4)));
      short8 k1 = *(const short8*)(KsB + (16 + lc) * 512 + (cb ^ ((lc & 7) << 4)));
      s0 = mfma16(k0, qf[kk], s0);
      s1 = mfma16(k1, qf[kk], s1);
    }
    float sv[8];
#pragma unroll
    for (int r = 0; r < 4; ++r) { sv[r] = s0[r]; sv[4 + r] = s1[r]; }
    if (kv0 + 31 > qr) {
#pragma unroll
      for (int f = 0; f < 2; ++f)
#pragma unroll
        for (int r = 0; r < 4; ++r) {
          int kvg = kv0 + f * 16 + lg * 4 + r;
          if (kvg > qr + lc) sv[f * 4 + r] = -1e30f;
        }
    }
    float m8 = fmaxf(fmaxf(fmaxf(sv[0], sv[1]), fmaxf(sv[2], sv[3])),
                     fmaxf(fmaxf(sv[4], sv[5]), fmaxf(sv[6], sv[7])));
    float pm = fmaxf(m8, __shfl_xor(m8, 16));
    pm = fmaxf(pm, __shfl_xor(pm, 32));
    if (__ballot(pm > mrow)) {
      float mn = fmaxf(mrow, pm);
      float alpha = __builtin_amdgcn_exp2f(mrow - mn);
      lrow *= alpha;
      float aa[4];
#pragma unroll
      for (int r = 0; r < 4; ++r) aa[r] = __shfl(alpha, lg * 4 + r);
#pragma unroll
      for (int nf = 0; nf < 16; ++nf) {
        f32x4 t4 = o[nf];
#pragma unroll
        for (int r = 0; r < 4; ++r) t4[r] *= aa[r];
        o[nf] = t4;
      }
      mrow = mn;
    }
    float p[8];
#pragma unroll
    for (int j = 0; j < 8; ++j) p[j] = __builtin_amdgcn_exp2f(sv[j] - mrow);
    float ps = ((p[0] + p[1]) + (p[2] + p[3])) + ((p[4] + p[5]) + (p[6] + p[7]));
    ps += __shfl_xor(ps, 16);
    ps += __shfl_xor(ps, 32);
    lrow += ps;
    asm volatile("" ::: "memory");
    Pw[lc * 20 + lg * 2 + 0] = cvtpk_bf16(p[0], p[1]);
    Pw[lc * 20 + lg * 2 + 1] = cvtpk_bf16(p[2], p[3]);
    Pw[lc * 20 + 8 + lg * 2 + 0] = cvtpk_bf16(p[4], p[5]);
    Pw[lc * 20 + 8 + lg * 2 + 1] = cvtpk_bf16(p[6], p[7]);
    asm volatile("" ::: "memory");
    short8 pf = *(const short8*)&Pm[lc * 40 + lg * 8];
#pragma unroll
    for (int nf = 0; nf < 16; ++nf) {
      const int d = nf * 16 + lc;
      short8 vf = *(const short8*)(VsB + d * 64 + ((lg * 16) ^ (((d >> 1) & 3) << 4)));
      o[nf] = mfma16(pf, vf, o[nf]);
    }
    asm volatile("" ::: "memory");
    __syncthreads();
  }

  float il = 1.0f / lrow;
  float ia[4];
#pragma unroll
  for (int r = 0; r < 4; ++r) ia[r] = __shfl(il, lg * 4 + r);
  const int crow0 = (bh >> 4) * 2048 + qr;
  const int ccol0 = (bh & 15) * 256;
#pragma unroll
  for (int nf = 0; nf < 16; ++nf)
#pragma unroll
    for (int r = 0; r < 4; ++r)
      ctx[(size_t)(crow0 + lg * 4 + r) * 4096 + ccol0 + nf * 16 + lc] =
          f2bf(o[nf][r] * ia[r]);
}

// ---------- launcher ----------
extern "C" void kernel_launch(void* const* d_in, const int* in_sizes, int n_in,
                              void* d_out, int out_size, void* d_ws, size_t ws_size,
                              hipStream_t stream) {
  const float* hidden = (const float*)d_in[0];
  const float* Wq = (const float*)d_in[1];
  const float* Wk = (const float*)d_in[2];
  const float* Wv = (const float*)d_in[3];
  const float* Wo = (const float*)d_in[4];
  const int* pos = (const int*)d_in[5];

  const size_t NEL = 16777216;  // 4096*4096
  if (ws_size < 6 * NEL * sizeof(u16)) return;  // need 192 MB scratch

  u16* hb = (u16*)d_ws;      // hidden bf16; reused as ctx after QKV GEMMs
  u16* wq = hb + NEL;
  u16* wk = wq + NEL;
  u16* wv = wk + NEL;
  u16* wo = wv + NEL;
  u16* vt = wo + NEL;        // V^T [bh][d][s]
  u16* ctx = hb;
  u16* qb = (u16*)d_out;     // Q,K live in d_out; overwritten by final GEMM
  u16* kb = qb + NEL;

  cvt_bf16<<<8192, 256, 0, stream>>>(hidden, hb);
  cvt_bf16<<<8192, 256, 0, stream>>>(Wq, wq);
  cvt_bf16<<<8192, 256, 0, stream>>>(Wk, wk);
  cvt_bf16<<<8192, 256, 0, stream>>>(Wv, wv);
  cvt_bf16<<<8192, 256, 0, stream>>>(Wo, wo);

  // Q pre-scaled by log2(e)/16 so flash softmax runs in exp2 domain.
  gemm_nt<0><<<256, 512, 0, stream>>>(hb, wq, qb, 0.09016844f);
  gemm_nt<0><<<256, 512, 0, stream>>>(hb, wk, kb, 1.0f);
  gemm_nt<1><<<256, 512, 0, stream>>>(hb, wv, vt, 1.0f);

  rope_qk<<<16384, 256, 0, stream>>>(qb, kb, pos);

  flash_attn<<<1024, 256, 0, stream>>>(qb, kb, vt, ctx);

  gemm_nt<2><<<256, 512, 0, stream>>>(ctx, wo, d_out, 1.0f);
}